// Round 5
// baseline (120.848 us; speedup 1.0000x reference)
//
#include <hip/hip_runtime.h>

// Sizes (static, from reference)
#define NSUB 65536
#define NV0 10242
#define NV1 40962
#define NV2 163842
#define EPSV 1e-5f
#define SPLITK 16
#define SLICE (NSUB / SPLITK)   // 4096

// Stats banking: per tensor, 64 slots x 16 floats. [0..C) = sum, [8..8+C) = sumsq.
#define NSLOT 64

__device__ inline float wave_red(float v) {
#pragma unroll
    for (int off = 32; off > 0; off >>= 1) v += __shfl_down(v, off, 64);
    return v;
}

// Consumer prologue: reduce 64x16 banked stats -> BN scale/shift in LDS.
// Wave 0 does the work; ends with __syncthreads().
template <int CIN>
__device__ inline void bn_prep(const float* __restrict__ stp, float n,
                               const float* __restrict__ g, const float* __restrict__ b,
                               float* sc, float* sh) {
    int t = threadIdx.x;
    if (t < 64) {
        const float* sp = stp + t * 16;
        float4 v0 = *(const float4*)(sp);
        float4 v1 = *(const float4*)(sp + 4);
        float4 v2 = *(const float4*)(sp + 8);
        float4 v3 = *(const float4*)(sp + 12);
        float r[16] = {v0.x, v0.y, v0.z, v0.w, v1.x, v1.y, v1.z, v1.w,
                       v2.x, v2.y, v2.z, v2.w, v3.x, v3.y, v3.z, v3.w};
#pragma unroll
        for (int i = 0; i < 16; ++i) r[i] = wave_red(r[i]);
        if (t == 0) {
#pragma unroll
            for (int c = 0; c < CIN; ++c) {
                float m = r[c] / n;
                float var = r[8 + c] / n - m * m;
                float scale = rsqrtf(var + EPSV) * g[c];
                sc[c] = scale;
                sh[c] = b[c] - m * scale;
            }
        }
    }
    __syncthreads();
}

// ---------------------------------------------------------------------------
// gemv1 split-K partials: y1p[s*256+o] = sub[slice s] . W_sub[o, slice s]
__global__ __launch_bounds__(256) void k_gemv1(const float* __restrict__ sub,
                                               const float* __restrict__ Ws,
                                               float* __restrict__ y1p) {
    int task = blockIdx.x, o = task >> 4, s = task & (SPLITK - 1);
    const float* row = Ws + (size_t)o * NSUB + s * SLICE;
    const float* sb = sub + s * SLICE;
    int t = threadIdx.x;
    int i0 = t * 4, i1 = (256 + t) * 4, i2 = (512 + t) * 4, i3 = (768 + t) * 4;
    float4 xa = *(const float4*)(sb + i0), wa = *(const float4*)(row + i0);
    float4 xb = *(const float4*)(sb + i1), wb = *(const float4*)(row + i1);
    float4 xc = *(const float4*)(sb + i2), wc = *(const float4*)(row + i2);
    float4 xd = *(const float4*)(sb + i3), wd = *(const float4*)(row + i3);
    float a0 = xa.x * wa.x + xa.y * wa.y + xa.z * wa.z + xa.w * wa.w;
    float a1 = xb.x * wb.x + xb.y * wb.y + xb.z * wb.z + xb.w * wb.w;
    float a2 = xc.x * wc.x + xc.y * wc.y + xc.z * wc.z + xc.w * wc.w;
    float a3 = xd.x * wd.x + xd.y * wd.y + xd.z * wd.z + xd.w * wd.w;
    float acc = wave_red((a0 + a1) + (a2 + a3));
    __shared__ float red[4];
    if ((t & 63) == 0) red[t >> 6] = acc;
    __syncthreads();
    if (t == 0) y1p[s * 256 + o] = red[0] + red[1] + red[2] + red[3];
}

// ---------------------------------------------------------------------------
// bridge: y1[o] = b_sub[o] + sum_s y1p[s][o]; zero st1..st4 atomic banks
__global__ __launch_bounds__(256) void k_bridge(const float* __restrict__ bs,
                                                const float* __restrict__ y1p,
                                                float* __restrict__ y1,
                                                float* __restrict__ stz) {
    int t = threadIdx.x;
    float acc = bs[t];
#pragma unroll
    for (int s = 0; s < SPLITK; ++s) acc += y1p[s * 256 + t];
    y1[t] = acc;
    for (int i = t; i < 4 * NSLOT * 16; i += 256) stz[i] = 0.f;
}

// ---------------------------------------------------------------------------
// x0[o] = y1 . W_fc[o,:] + b_fc[o]; wave per output
__global__ __launch_bounds__(256) void k_gemv2(const float* __restrict__ y1,
                                               const float* __restrict__ Wf,
                                               const float* __restrict__ bfc,
                                               float* __restrict__ x0) {
    int o = blockIdx.x * 4 + (threadIdx.x >> 6);
    int ln = threadIdx.x & 63;
    if (o >= 3 * NV0) return;
    const float* row = Wf + (size_t)o * 256;
    float4 w4 = *(const float4*)(row + ln * 4);
    float4 yv = *(const float4*)(y1 + ln * 4);
    float acc = wave_red(w4.x * yv.x + w4.y * yv.y + w4.z * yv.z + w4.w * yv.w);
    if (ln == 0) x0[o] = acc + bfc[o];
}

// ---------------------------------------------------------------------------
// banked stats for x0 [n,3]: exactly 64 blocks; block b fully writes slot b
__global__ __launch_bounds__(256) void k_stats3(const float* __restrict__ x, int n,
                                                float* __restrict__ stp) {
    int t = threadIdx.x;
    float s0 = 0, s1 = 0, s2 = 0, q0 = 0, q1 = 0, q2 = 0;
    for (int v = blockIdx.x * 256 + t; v < n; v += NSLOT * 256) {
        float a = x[v * 3 + 0], b = x[v * 3 + 1], c = x[v * 3 + 2];
        s0 += a; s1 += b; s2 += c;
        q0 += a * a; q1 += b * b; q2 += c * c;
    }
    s0 = wave_red(s0); s1 = wave_red(s1); s2 = wave_red(s2);
    q0 = wave_red(q0); q1 = wave_red(q1); q2 = wave_red(q2);
    __shared__ float ls[4][6];
    int wv = t >> 6, ln = t & 63;
    if (ln == 0) {
        ls[wv][0] = s0; ls[wv][1] = s1; ls[wv][2] = s2;
        ls[wv][3] = q0; ls[wv][4] = q1; ls[wv][5] = q2;
    }
    __syncthreads();
    if (t == 0) {
        float* sp = stp + blockIdx.x * 16;
#pragma unroll
        for (int i = 0; i < 16; ++i) sp[i] = 0.f;
        sp[0] = ls[0][0] + ls[1][0] + ls[2][0] + ls[3][0];
        sp[1] = ls[0][1] + ls[1][1] + ls[2][1] + ls[3][1];
        sp[2] = ls[0][2] + ls[1][2] + ls[2][2] + ls[3][2];
        sp[8] = ls[0][3] + ls[1][3] + ls[2][3] + ls[3][3];
        sp[9] = ls[0][4] + ls[1][4] + ls[2][4] + ls[3][4];
        sp[10] = ls[0][5] + ls[1][5] + ls[2][5] + ls[3][5];
    }
}

// ---------------------------------------------------------------------------
// upconv + fused output stats (banked atomics)
__global__ __launch_bounds__(256) void k_upconv(const float* __restrict__ xin, int nIn, int nOut,
                                                const float* __restrict__ stp_in,
                                                float* __restrict__ stp_out,
                                                const float* __restrict__ g, const float* __restrict__ b,
                                                const float* __restrict__ W, const float* __restrict__ bias,
                                                const int* __restrict__ top, const int* __restrict__ down,
                                                float* __restrict__ xout) {
    __shared__ float sW[63], sB[21], sc[3], sh[3];
    int t = threadIdx.x;
    if (t >= 64 && t < 127) sW[t - 64] = W[t - 64];
    if (t >= 128 && t < 149) sB[t - 128] = bias[t - 128];
    bn_prep<3>(stp_in, (float)nIn, g, b, sc, sh);

    int v = blockIdx.x * 256 + t;
    bool ok = v < nOut;
    float o0 = 0.f, o1 = 0.f, o2 = 0.f;

    auto uval = [&](int idx, float* o3) {
        int src = idx / 7;
        int j = idx - src * 7;
        float a0 = xin[src * 3 + 0] * sc[0] + sh[0]; a0 = a0 > 0.f ? a0 : 0.2f * a0;
        float a1 = xin[src * 3 + 1] * sc[1] + sh[1]; a1 = a1 > 0.f ? a1 : 0.2f * a1;
        float a2 = xin[src * 3 + 2] * sc[2] + sh[2]; a2 = a2 > 0.f ? a2 : 0.2f * a2;
#pragma unroll
        for (int c = 0; c < 3; ++c) {
            int r = j * 3 + c;
            o3[c] = sB[r] + a0 * sW[r * 3 + 0] + a1 * sW[r * 3 + 1] + a2 * sW[r * 3 + 2];
        }
    };

    if (ok) {
        if (v < nIn) {
            float o3[3];
            uval(top[v], o3);
            o0 = o3[0]; o1 = o3[1]; o2 = o3[2];
        } else {
            int i = v - nIn;
            float a[3], bb[3];
            uval(down[2 * i], a);
            uval(down[2 * i + 1], bb);
            o0 = 0.5f * (a[0] + a[1]);
            o1 = 0.5f * (a[2] + bb[0]);
            o2 = 0.5f * (bb[1] + bb[2]);
        }
        xout[(size_t)v * 3 + 0] = o0;
        xout[(size_t)v * 3 + 1] = o1;
        xout[(size_t)v * 3 + 2] = o2;
    }
    // fused stats of outputs
    float q0 = o0 * o0, q1 = o1 * o1, q2 = o2 * o2;
    float r0 = wave_red(o0), r1 = wave_red(o1), r2 = wave_red(o2);
    float p0 = wave_red(q0), p1 = wave_red(q1), p2 = wave_red(q2);
    if ((t & 63) == 0) {
        float* sp = stp_out + (blockIdx.x & (NSLOT - 1)) * 16;
        atomicAdd(sp + 0, r0); atomicAdd(sp + 1, r1); atomicAdd(sp + 2, r2);
        atomicAdd(sp + 8, p0); atomicAdd(sp + 9, p1); atomicAdd(sp + 10, p2);
    }
}

// ---------------------------------------------------------------------------
// one-ring conv + optional fused output stats
template <int CIN, int COUT, bool STATS>
__global__ __launch_bounds__(256) void k_onering(const float* __restrict__ xin,
                                                 const float* __restrict__ stp_in, int n,
                                                 float* __restrict__ stp_out,
                                                 const float* __restrict__ g, const float* __restrict__ b,
                                                 const float* __restrict__ W, const float* __restrict__ bias,
                                                 const int* __restrict__ neigh,
                                                 float* __restrict__ out) {
    __shared__ float sW[COUT * 7 * CIN], sB[COUT], sc[CIN], sh[CIN];
    int t = threadIdx.x;
    for (int i = t; i < COUT * 7 * CIN; i += 256) sW[i] = W[i];
    if (t >= 64 && t < 64 + COUT) sB[t - 64] = bias[t - 64];
    bn_prep<CIN>(stp_in, (float)n, g, b, sc, sh);

    int v = blockIdx.x * 256 + t;
    bool ok = v < n;
    float acc[COUT];
#pragma unroll
    for (int c = 0; c < COUT; ++c) acc[c] = ok ? sB[c] : 0.f;

    if (ok) {
#pragma unroll
        for (int j = 0; j < 7; ++j) {
            int nb = neigh[v * 7 + j];
            float tv[CIN];
            if (CIN == 8) {
                float4 A = *(const float4*)(xin + (size_t)nb * 8);
                float4 B = *(const float4*)(xin + (size_t)nb * 8 + 4);
                float raw[8] = {A.x, A.y, A.z, A.w, B.x, B.y, B.z, B.w};
#pragma unroll
                for (int k = 0; k < CIN; ++k) {
                    float x = raw[k] * sc[k] + sh[k];
                    tv[k] = x > 0.f ? x : 0.2f * x;
                }
            } else {
#pragma unroll
                for (int k = 0; k < CIN; ++k) {
                    float x = xin[(size_t)nb * CIN + k] * sc[k] + sh[k];
                    tv[k] = x > 0.f ? x : 0.2f * x;
                }
            }
#pragma unroll
            for (int c = 0; c < COUT; ++c) {
                float a = acc[c];
#pragma unroll
                for (int k = 0; k < CIN; ++k) a += tv[k] * sW[c * 7 * CIN + j * CIN + k];
                acc[c] = a;
            }
        }
        if (COUT == 8) {
            float4 A = {acc[0], acc[1], acc[2], acc[3]};
            float4 B = {acc[4], acc[5], acc[6], acc[7]};
            *(float4*)(out + (size_t)v * 8) = A;
            *(float4*)(out + (size_t)v * 8 + 4) = B;
        } else {
#pragma unroll
            for (int c = 0; c < COUT; ++c) out[(size_t)v * COUT + c] = acc[c];
        }
    }

    if (STATS) {
        float r[16];
#pragma unroll
        for (int i = 0; i < 16; ++i) r[i] = 0.f;
#pragma unroll
        for (int c = 0; c < COUT; ++c) {
            float val = ok ? acc[c] : 0.f;
            r[c] = val;
            r[8 + c] = val * val;
        }
#pragma unroll
        for (int i = 0; i < 16; ++i) r[i] = wave_red(r[i]);
        if ((t & 63) == 0) {
            float* sp = stp_out + (blockIdx.x & (NSLOT - 1)) * 16;
#pragma unroll
            for (int c = 0; c < COUT; ++c) {
                atomicAdd(sp + c, r[c]);
                atomicAdd(sp + 8 + c, r[8 + c]);
            }
        }
    }
}

// ---------------------------------------------------------------------------
extern "C" void kernel_launch(void* const* d_in, const int* in_sizes, int n_in,
                              void* d_out, int out_size, void* d_ws, size_t ws_size,
                              hipStream_t stream) {
    const float* sub_id = (const float*)d_in[0];
    const float* W_sub  = (const float*)d_in[1];
    const float* b_sub  = (const float*)d_in[2];
    const float* W_fc   = (const float*)d_in[3];
    const float* b_fc   = (const float*)d_in[4];
    const float* bn_u0g = (const float*)d_in[5];
    const float* bn_u0b = (const float*)d_in[6];
    const float* up0_W  = (const float*)d_in[7];
    const float* up0_b  = (const float*)d_in[8];
    const float* bn_u1g = (const float*)d_in[9];
    const float* bn_u1b = (const float*)d_in[10];
    const float* up1_W  = (const float*)d_in[11];
    const float* up1_b  = (const float*)d_in[12];
    const float* bn0g   = (const float*)d_in[13];
    const float* bn0b   = (const float*)d_in[14];
    const float* c0_W   = (const float*)d_in[15];
    const float* c0_b   = (const float*)d_in[16];
    const float* bn1g   = (const float*)d_in[17];
    const float* bn1b   = (const float*)d_in[18];
    const float* c1_W   = (const float*)d_in[19];
    const float* c1_b   = (const float*)d_in[20];
    const float* bn2g   = (const float*)d_in[21];
    const float* bn2b   = (const float*)d_in[22];
    const float* c2_W   = (const float*)d_in[23];
    const float* c2_b   = (const float*)d_in[24];
    const int* neigh  = (const int*)d_in[25];
    const int* top0   = (const int*)d_in[26];
    const int* down0  = (const int*)d_in[27];
    const int* top1   = (const int*)d_in[28];
    const int* down1  = (const int*)d_in[29];

    float* ws = (float*)d_ws;
    float* y1p = ws;                      // 4096
    float* y1  = y1p + 4096;              // 256
    float* x0  = y1 + 256;                // 30726
    float* xA  = x0 + 30726;              // 122886
    float* xB  = xA + 122886;             // 491526
    float* h0  = xB + 491526;             // 1310736
    float* h1  = h0 + 1310736;            // 1310736
    float* stp = h1 + 1310736;            // 5 regions x 64 slots x 16
    float* st0 = stp;                     // x0 stats (full-write by k_stats3)
    float* st1 = stp + 1 * NSLOT * 16;    // xA (atomics)
    float* st2 = stp + 2 * NSLOT * 16;    // xB
    float* st3 = stp + 3 * NSLOT * 16;    // h0
    float* st4 = stp + 4 * NSLOT * 16;    // h1

    k_gemv1<<<256 * SPLITK, 256, 0, stream>>>(sub_id, W_sub, y1p);
    k_bridge<<<1, 256, 0, stream>>>(b_sub, y1p, y1, st1);   // zeroes st1..st4
    k_gemv2<<<(3 * NV0 + 3) / 4, 256, 0, stream>>>(y1, W_fc, b_fc, x0);
    k_stats3<<<NSLOT, 256, 0, stream>>>(x0, NV0, st0);

    k_upconv<<<(NV1 + 255) / 256, 256, 0, stream>>>(x0, NV0, NV1, st0, st1,
                                                    bn_u0g, bn_u0b, up0_W, up0_b,
                                                    top0, down0, xA);
    k_upconv<<<(NV2 + 255) / 256, 256, 0, stream>>>(xA, NV1, NV2, st1, st2,
                                                    bn_u1g, bn_u1b, up1_W, up1_b,
                                                    top1, down1, xB);

    k_onering<3, 8, true><<<(NV2 + 255) / 256, 256, 0, stream>>>(
        xB, st2, NV2, st3, bn0g, bn0b, c0_W, c0_b, neigh, h0);
    k_onering<8, 8, true><<<(NV2 + 255) / 256, 256, 0, stream>>>(
        h0, st3, NV2, st4, bn1g, bn1b, c1_W, c1_b, neigh, h1);
    k_onering<8, 2, false><<<(NV2 + 255) / 256, 256, 0, stream>>>(
        h1, st4, NV2, nullptr, bn2g, bn2b, c2_W, c2_b, neigh, (float*)d_out);
}